// Round 14
// baseline (699.176 us; speedup 1.0000x reference)
//
#include <hip/hip_runtime.h>

#define Bv   2
#define Dd   160
#define Hh   192
#define Ww   160
#define HW   (Hh*Ww)          // 30720
#define DHW  (Dd*Hh*Ww)       // 4915200
#define NTOT (Bv*DHW)         // 9830400
#define INV729 (1.0f/729.0f)

typedef _Float16 f16;

// ---- vector helpers: storage type TS in {float, f16}, all math in f32 ----
__device__ __forceinline__ float4 LD4(const float* p) {
    return *reinterpret_cast<const float4*>(p);
}
__device__ __forceinline__ float4 LD4(const f16* p) {
    union { uint2 u; f16 h[4]; } c;
    c.u = *reinterpret_cast<const uint2*>(p);
    return make_float4((float)c.h[0], (float)c.h[1], (float)c.h[2], (float)c.h[3]);
}
__device__ __forceinline__ void ST4(float* p, float4 v) {
    *reinterpret_cast<float4*>(p) = v;
}
__device__ __forceinline__ void ST4(f16* p, float4 v) {
    union { uint2 u; f16 h[4]; } c;
    c.h[0] = (f16)v.x; c.h[1] = (f16)v.y; c.h[2] = (f16)v.z; c.h[3] = (f16)v.w;
    *reinterpret_cast<uint2*>(p) = c.u;
}
__device__ __forceinline__ float4 add4(float4 a, float4 b) {
    return make_float4(a.x+b.x, a.y+b.y, a.z+b.z, a.w+b.w);
}
__device__ __forceinline__ float4 mul4(float4 a, float4 b) {
    return make_float4(a.x*b.x, a.y*b.y, a.z*b.z, a.w*b.w);
}
__device__ __forceinline__ float4 fma4(float4 s, float w, float4 v) {
    return make_float4(fmaf(w,v.x,s.x), fmaf(w,v.y,s.y), fmaf(w,v.z,s.z), fmaf(w,v.w,s.w));
}
__device__ __forceinline__ float4 zero4() { return make_float4(0.f,0.f,0.f,0.f); }

// ---- loadrow: fetch the 12-wide x-window (3 vec4 each for I and J) ----
__device__ __forceinline__ void loadrow(const float* __restrict__ rI,
                                        const float* __restrict__ rJ,
                                        int x0, float4 vI[3], float4 vJ[3]) {
    if (x0 >= 4 && x0 <= Ww - 8) {                     // fast interior path
        vI[0] = LD4(rI + x0 - 4); vI[1] = LD4(rI + x0); vI[2] = LD4(rI + x0 + 4);
        vJ[0] = LD4(rJ + x0 - 4); vJ[1] = LD4(rJ + x0); vJ[2] = LD4(rJ + x0 + 4);
    } else {
        float wI[12], wJ[12];
        #pragma unroll
        for (int i = 0; i < 12; ++i) {
            int xx = x0 - 4 + i;
            bool ok = (xx >= 0) && (xx < Ww);
            wI[i] = ok ? rI[xx] : 0.f;
            wJ[i] = ok ? rJ[xx] : 0.f;
        }
        vI[0] = make_float4(wI[0],wI[1],wI[2],wI[3]);
        vI[1] = make_float4(wI[4],wI[5],wI[6],wI[7]);
        vI[2] = make_float4(wI[8],wI[9],wI[10],wI[11]);
        vJ[0] = make_float4(wJ[0],wJ[1],wJ[2],wJ[3]);
        vJ[1] = make_float4(wJ[4],wJ[5],wJ[6],wJ[7]);
        vJ[2] = make_float4(wJ[8],wJ[9],wJ[10],wJ[11]);
    }
}

// ---- accum5: S += sgn * (5-channel 9-wide x-box-sums), float4-tree form ----
__device__ __forceinline__ void accum5(const float4 vI[3], const float4 vJ[3],
                                       float sgn, float4 S[5]) {
#define CH(cidx, E0, E1, E2) {                                              \
        float4 t0 = (E0), t1 = (E1), t2 = (E2);                             \
        float4 w = add4(t0, t1);                                            \
        float s0 = ((w.x + w.y) + (w.z + w.w)) + t2.x;                      \
        float s1 = s0 - t0.x + t2.y;                                        \
        float s2 = s1 - t0.y + t2.z;                                        \
        float s3 = s2 - t0.z + t2.w;                                        \
        S[cidx] = fma4(S[cidx], sgn, make_float4(s0, s1, s2, s3));          \
    }
    CH(0, vI[0], vI[1], vI[2]);
    CH(1, vJ[0], vJ[1], vJ[2]);
    CH(2, mul4(vI[0],vI[0]), mul4(vI[1],vI[1]), mul4(vI[2],vI[2]));
    CH(3, mul4(vJ[0],vJ[0]), mul4(vJ[1],vJ[1]), mul4(vJ[2],vJ[2]));
    CH(4, mul4(vI[0],vJ[0]), mul4(vI[1],vJ[1]), mul4(vI[2],vJ[2]));
#undef CH
}

// ---- cc4: finalize 4 voxels from 5-channel window sums, return their cc sum ----
__device__ __forceinline__ float cc4(const float4 S[5]) {
    float acc = 0.f;
#define FIN(CMP) {                                                      \
        float SI = S[0].CMP, SJ = S[1].CMP, SII = S[2].CMP,             \
              SJJ = S[3].CMP, SIJ = S[4].CMP;                           \
        float uI = SI * INV729, uJ = SJ * INV729;                       \
        float cross = SIJ - uJ * SI - uI * SJ + uI * uJ * 729.0f;       \
        float Iv = SII - 2.0f * uI * SI + uI * uI * 729.0f;             \
        float Jv = SJJ - 2.0f * uJ * SJ + uJ * uJ * 729.0f;             \
        acc += cross * cross / (Iv * Jv + 1e-5f);                       \
    }
    FIN(x) FIN(y) FIN(z) FIN(w)
#undef FIN
    return acc;
}

__device__ __forceinline__ void block_reduce_atomic(float acc, float* out) {
    for (int off = 32; off > 0; off >>= 1) acc += __shfl_down(acc, off);
    __shared__ float red[4];
    int lane = threadIdx.x & 63, wid = threadIdx.x >> 6;
    if (lane == 0) red[wid] = acc;
    __syncthreads();
    if (threadIdx.x == 0)
        atomicAdd(out, (red[0]+red[1]+red[2]+red[3]) * (1.0f/(float)NTOT));
}

// ---------------- k12: fused x+y pass, software-pipelined (distance 2) -------
// y-chunk 16, 600 blocks (grid-capped occupancy -> VGPR for prefetch is free).
// Steady loop is branch-free: clamped row addresses + zero weights at edges.
template<typename TS>
__global__ __launch_bounds__(256, 2)
void k12_xy(const float* __restrict__ I, const float* __restrict__ J,
            TS* __restrict__ B) {
    int tid = blockIdx.x * 256 + threadIdx.x;          // 0 .. 153599
    int x4 = tid % (Ww/4);  int t1 = tid / (Ww/4);
    int yc = t1 % (Hh/16);  t1 /= (Hh/16);
    int z  = t1 % Dd;       int b = t1 / Dd;
    int x0 = x4 * 4, y0 = yc * 16;

    const float* sI = I + (size_t)b * DHW + (size_t)z * HW;
    const float* sJ = J + (size_t)b * DHW + (size_t)z * HW;
    TS* dst = B + (size_t)b * DHW + (size_t)z * HW + x0;

    float4 S[5] = {zero4(), zero4(), zero4(), zero4(), zero4()};

    // initial window: rows y0-4 .. y0+3
    #pragma unroll
    for (int dy = -4; dy <= 3; ++dy) {
        int y = y0 + dy;
        if (y >= 0) {
            float4 vI[3], vJ[3];
            loadrow(sI + (size_t)y * Ww, sJ + (size_t)y * Ww, x0, vI, vJ);
            accum5(vI, vJ, 1.f, S);
        }
    }

    // prefetch pipeline: a = add-rows (y+4), b = sub-rows (y-4), depth 2
    float4 aI[2][3], aJ[2][3], bI[2][3], bJ[2][3];
    #pragma unroll
    for (int k = 0; k < 2; ++k) {
        int yt = y0 + 4 + k; if (yt > Hh - 1) yt = Hh - 1;
        int yo = y0 - 4 + k; if (yo < 0) yo = 0;
        loadrow(sI + (size_t)yt * Ww, sJ + (size_t)yt * Ww, x0, aI[k], aJ[k]);
        loadrow(sI + (size_t)yo * Ww, sJ + (size_t)yo * Ww, x0, bI[k], bJ[k]);
    }

    #pragma unroll
    for (int k = 0; k < 16; ++k) {
        int y = y0 + k;
        // issue loads for iteration k+2 before consuming iteration k
        float4 nI[3], nJ[3], mI[3], mJ[3];
        if (k < 14) {
            int yt = y + 6; if (yt > Hh - 1) yt = Hh - 1;
            int yo = y - 2; if (yo < 0) yo = 0;
            loadrow(sI + (size_t)yt * Ww, sJ + (size_t)yt * Ww, x0, nI, nJ);
            loadrow(sI + (size_t)yo * Ww, sJ + (size_t)yo * Ww, x0, mI, mJ);
        }
        float wA = (y + 4) < Hh ? 1.f : 0.f;
        float wS = (y - 4) >= 0 ? -1.f : 0.f;

        accum5(aI[0], aJ[0], wA, S);                   // S now covers y-4..y+4
        ST4(dst + (size_t)y * Ww,                    S[0]);
        ST4(dst + (size_t)NTOT     + (size_t)y * Ww, S[1]);
        ST4(dst + (size_t)2 * NTOT + (size_t)y * Ww, S[2]);
        ST4(dst + (size_t)3 * NTOT + (size_t)y * Ww, S[3]);
        ST4(dst + (size_t)4 * NTOT + (size_t)y * Ww, S[4]);
        accum5(bI[0], bJ[0], wS, S);                   // drop row y-4

        // shift pipeline (all indices compile-time under full unroll -> SSA)
        #pragma unroll
        for (int j = 0; j < 3; ++j) {
            aI[0][j] = aI[1][j]; aJ[0][j] = aJ[1][j];
            bI[0][j] = bI[1][j]; bJ[0][j] = bJ[1][j];
        }
        if (k < 14) {
            #pragma unroll
            for (int j = 0; j < 3; ++j) {
                aI[1][j] = nI[j]; aJ[1][j] = nJ[j];
                bI[1][j] = mI[j]; bJ[1][j] = mJ[j];
            }
        }
    }
}

// ---------------- k3: z-pass + finalize, software-pipelined (distance 1) -----
// z-chunk 8, 1200 blocks, f16 reads (L3-resident). Branch-free steady loop.
template<typename TS>
__global__ __launch_bounds__(256, 4)
void k3_zpass(const TS* __restrict__ Bb, float* __restrict__ out) {
    int tid = blockIdx.x * 256 + threadIdx.x;          // 0 .. 307199
    int x4 = tid % (Ww/4);  int t1 = tid / (Ww/4);
    int y  = t1 % Hh;       t1 /= Hh;
    int zc = t1 % (Dd/8);   int b = t1 / (Dd/8);
    int z0 = zc * 8;

    size_t base = (size_t)b * DHW + (size_t)y * Ww + x4 * 4;
    const TS* P0 = Bb + base;

    float4 S[5] = {zero4(), zero4(), zero4(), zero4(), zero4()};

    // initial window: slices z0-4 .. z0+3
    #pragma unroll
    for (int dz = -4; dz <= 3; ++dz) {
        int z = z0 + dz;
        if (z >= 0) {
            const TS* pp = P0 + (size_t)z * HW;
            #pragma unroll
            for (int c = 0; c < 5; ++c) S[c] = add4(S[c], LD4(pp + (size_t)c * NTOT));
        }
    }

    // prefetch first add/sub slices
    float4 A[5], Bf[5];
    {
        int zt = z0 + 4; if (zt > Dd - 1) zt = Dd - 1;
        int zo = z0 - 4; if (zo < 0) zo = 0;
        const TS* pa = P0 + (size_t)zt * HW;
        const TS* pb = P0 + (size_t)zo * HW;
        #pragma unroll
        for (int c = 0; c < 5; ++c) {
            A[c]  = LD4(pa + (size_t)c * NTOT);
            Bf[c] = LD4(pb + (size_t)c * NTOT);
        }
    }

    float acc = 0.f;
    #pragma unroll
    for (int k = 0; k < 8; ++k) {
        int z = z0 + k;
        float4 nA[5], nB[5];
        if (k < 7) {                                   // issue next slice loads
            int zt = z + 5; if (zt > Dd - 1) zt = Dd - 1;
            int zo = z - 3; if (zo < 0) zo = 0;
            const TS* pa = P0 + (size_t)zt * HW;
            const TS* pb = P0 + (size_t)zo * HW;
            #pragma unroll
            for (int c = 0; c < 5; ++c) {
                nA[c] = LD4(pa + (size_t)c * NTOT);
                nB[c] = LD4(pb + (size_t)c * NTOT);
            }
        }
        float wA = (z + 4) < Dd  ? 1.f  : 0.f;
        float wS = (z - 4) >= 0 ? -1.f : 0.f;
        #pragma unroll
        for (int c = 0; c < 5; ++c) S[c] = fma4(S[c], wA, A[c]);
        acc += cc4(S);
        #pragma unroll
        for (int c = 0; c < 5; ++c) S[c] = fma4(S[c], wS, Bf[c]);
        if (k < 7) {
            #pragma unroll
            for (int c = 0; c < 5; ++c) { A[c] = nA[c]; Bf[c] = nB[c]; }
        }
    }

    block_reduce_atomic(acc, out);
}

// ---------------- brute-force fallback: ZERO workspace, slow but correct ----
__global__ __launch_bounds__(256)
void k_brute(const float* __restrict__ I, const float* __restrict__ J,
             float* __restrict__ out) {
    int tid = blockIdx.x * 256 + threadIdx.x;          // 0 .. NTOT/4-1
    int x4 = tid % (Ww/4);  int t1 = tid / (Ww/4);
    int y  = t1 % Hh;       t1 /= Hh;
    int z  = t1 % Dd;       int b = t1 / Dd;
    int x0 = x4 * 4;

    const float* bI = I + (size_t)b * DHW;
    const float* bJ = J + (size_t)b * DHW;

    float4 S[5] = {zero4(), zero4(), zero4(), zero4(), zero4()};
    for (int dz = -4; dz <= 4; ++dz) {
        int zz = z + dz;
        if (zz < 0 || zz >= Dd) continue;
        for (int dy = -4; dy <= 4; ++dy) {
            int yy = y + dy;
            if (yy < 0 || yy >= Hh) continue;
            float4 vI[3], vJ[3];
            loadrow(bI + (size_t)zz * HW + (size_t)yy * Ww,
                    bJ + (size_t)zz * HW + (size_t)yy * Ww, x0, vI, vJ);
            accum5(vI, vJ, 1.f, S);
        }
    }
    block_reduce_atomic(cc4(S), out);
}

extern "C" void kernel_launch(void* const* d_in, const int* in_sizes, int n_in,
                              void* d_out, int out_size, void* d_ws, size_t ws_size,
                              hipStream_t stream) {
    const float* I = (const float*)d_in[0];
    const float* J = (const float*)d_in[1];
    float* out = (float*)d_out;

    hipMemsetAsync(d_out, 0, sizeof(float), stream);   // graph-capture-safe

    const int g12 = 153600/256;                        // 600 blocks
    const int g3  = 307200/256;                        // 1200 blocks

    if (ws_size >= (size_t)5 * NTOT * sizeof(f16)) {
        // f16 intermediates (98.3 MB), all math f32 (rounds 10/13: absmax 0.0).
        f16* B = (f16*)d_ws;
        k12_xy<f16><<<g12, 256, 0, stream>>>(I, J, B);
        k3_zpass<f16><<<g3, 256, 0, stream>>>(B, out);
    } else {
        // workspace-free fallback: slow but correct
        k_brute<<<(NTOT/4)/256, 256, 0, stream>>>(I, J, out);
    }
}